// Round 15
// baseline (331.167 us; speedup 1.0000x reference)
//
#include <hip/hip_runtime.h>
#include <math.h>

#define N_NODES 20000
#define E_EDGES 320000
#define EP (E_EDGES + N_NODES)   // 340000 edges incl. self-loops
#define D 256
#define NHEAD 4
#define CH 64
#define NEG_SLOPE 0.2f
#define LN_EPS 1e-5f

typedef _Float16 half8_t __attribute__((ext_vector_type(8)));
typedef _Float16 half4_t __attribute__((ext_vector_type(4)));
typedef _Float16 half2_t __attribute__((ext_vector_type(2)));
typedef float   float4_t __attribute__((ext_vector_type(4)));

#define SCATTER_BLOCKS ((EP + 255) / 256)   // 1329

__device__ __forceinline__ void async_cp16(const void* g, void* l)
{
    __builtin_amdgcn_global_load_lds(
        (const __attribute__((address_space(1))) void*)g,
        (__attribute__((address_space(3))) void*)l, 16, 0, 0);
}

// ---- DPP row_ror reduction over 16-lane rows (pure VALU, no LDS pipe) ----
template<int CTRL>
__device__ __forceinline__ float dpp_add(float v) {
    int t = __builtin_amdgcn_update_dpp(0, __float_as_int(v), CTRL, 0xF, 0xF, true);
    return v + __int_as_float(t);
}
__device__ __forceinline__ float row_sum16(float v) {
    v = dpp_add<0x121>(v);   // ror 1
    v = dpp_add<0x122>(v);   // ror 2
    v = dpp_add<0x124>(v);   // ror 4
    v = dpp_add<0x128>(v);   // ror 8
    return v;
}

// ===== one-time: convert x (fp32) -> f16 AND histogram degrees =====
// (deg must be pre-zeroed via hipMemsetAsync before this kernel)
__global__ __launch_bounds__(256)
void convert_hist_kernel(const float* __restrict__ x, _Float16* __restrict__ h16,
                         const int* __restrict__ ei, int* __restrict__ deg)
{
    int i = blockIdx.x * 256 + threadIdx.x;
    if (i < EP) {
        int dst = (i < E_EDGES) ? ei[E_EDGES + i] : (i - E_EDGES);
        atomicAdd(&deg[dst], 1);
    }
    if (i >= N_NODES * D / 4) return;
    float4 v = reinterpret_cast<const float4*>(x)[i];
    half4_t o;
    o.x = (_Float16)v.x; o.y = (_Float16)v.y; o.z = (_Float16)v.z; o.w = (_Float16)v.w;
    reinterpret_cast<half4_t*>(h16)[i] = o;
}

// single-pass block scan, LDS-staged for coalesced global access.
// 4 chunks of 5120 nodes; thread t owns 5 consecutive nodes per chunk.
__global__ __launch_bounds__(1024)
void csr_scan_kernel(const int* __restrict__ deg, int* __restrict__ rowptr,
                     int* __restrict__ cursor, int* __restrict__ csr_src)
{
    __shared__ int buf[5120];
    __shared__ int wsum[16];
    __shared__ int carry_s;
    int t = threadIdx.x, lane = t & 63, w = t >> 6;
    if (t == 0) carry_s = 0;
    if (t < 8) csr_src[EP + t] = 0;      // slack for masked tail over-reads

    for (int c = 0; c < 4; ++c) {
        int base = c * 5120;
        // coalesced load (stride-1 across lanes)
        #pragma unroll
        for (int k = 0; k < 5; ++k) {
            int idx = base + k * 1024 + t;
            buf[k * 1024 + t] = (idx < N_NODES) ? deg[idx] : 0;
        }
        __syncthreads();
        int loc[5]; int s = 0;
        #pragma unroll
        for (int k = 0; k < 5; ++k) { loc[k] = buf[t * 5 + k]; s += loc[k]; }
        int x = s;
        #pragma unroll
        for (int o = 1; o < 64; o <<= 1) {
            int y = __shfl_up(x, o, 64);
            if (lane >= o) x += y;
        }
        if (lane == 63) wsum[w] = x;
        __syncthreads();                  // also: all lanes done reading buf
        if (t == 0) {
            int sa = carry_s;
            #pragma unroll
            for (int k = 0; k < 16; ++k) { int tmp = wsum[k]; wsum[k] = sa; sa += tmp; }
            carry_s = sa;
        }
        __syncthreads();
        int excl = wsum[w] + x - s;
        #pragma unroll
        for (int k = 0; k < 5; ++k) { buf[t * 5 + k] = excl; excl += loc[k]; }
        __syncthreads();
        // coalesced store of rowptr and cursor
        #pragma unroll
        for (int k = 0; k < 5; ++k) {
            int idx = base + k * 1024 + t;
            if (idx < N_NODES) {
                int v = buf[k * 1024 + t];
                rowptr[idx] = v;
                cursor[idx] = v;
            }
        }
        __syncthreads();                  // buf reused next chunk
    }
    if (t == 0) rowptr[N_NODES] = carry_s;
}

// ===== fused: CSR scatter (blocks < SCATTER_BLOCKS) + weight convert/transpose =====
struct WPtrs { const float* p[8]; };
__global__ __launch_bounds__(256)
void scatter_convw_kernel(const int* __restrict__ ei, int* __restrict__ cursor,
                          int* __restrict__ csr_src, WPtrs wp,
                          _Float16* __restrict__ Wt_all)
{
    if (blockIdx.x < SCATTER_BLOCKS) {
        int e = blockIdx.x * 256 + threadIdx.x;
        if (e >= EP) return;
        int src, dst;
        if (e < E_EDGES) { src = ei[e]; dst = ei[E_EDGES + e]; }
        else             { src = dst = e - E_EDGES; }
        int pos = atomicAdd(&cursor[dst], 1);
        csr_src[pos] = src;
        return;
    }
    // weight convert: 128 blocks mapped to (bx, by, z) = (4, 4, 8)
    __shared__ float tile[64][65];
    int bz = blockIdx.x - SCATTER_BLOCKS;
    int bxi = bz & 3, byi = (bz >> 2) & 3, z = bz >> 4;
    const float* W = wp.p[z];
    _Float16* out = Wt_all + (size_t)z * 65536;
    int bx = bxi * 64, by = byi * 64;
    int t = threadIdx.x;
    #pragma unroll
    for (int i = 0; i < 16; ++i) {
        int idx = t + i * 256;
        int kk = idx >> 6, nn = idx & 63;
        tile[kk][nn] = W[(by + kk) * 256 + bx + nn];
    }
    __syncthreads();
    #pragma unroll
    for (int i = 0; i < 16; ++i) {
        int idx = t + i * 256;
        int nn = idx >> 6, kk = idx & 63;
        out[(bx + nn) * 256 + by + kk] = (_Float16)tile[kk][nn];
    }
}

// ================= GEMM: X = A16 @ W (f16 MFMA, fp32 accum, f16 out) =================
// A16: [M][256] f16 row-major; Wt: [256][256] f16 laid out [n][k].
// BM=64, BN=128, BK=64. 1252 active blocks @ 24 KB LDS -> ~6 blocks/CU
// capacity: ALL blocks co-resident in one round (no straggler tail).
// Flat id swizzled so the 4 (col,mat) blocks sharing an A row-block share
// id mod 8 -> same XCD L2 (A tile fetched once per XCD).
// 4 waves as 2x2: wave (wy,wx) owns 32 rows x 64 cols.
#define BM 64
#define BN 128
#define BK 64
#define NRB 313    // ceil(20000/64) row blocks
#define EPAD2 72   // epilogue LDS row stride in f16 (144 B)
__global__ __launch_bounds__(256)
void gemm_f16_kernel(const _Float16* __restrict__ A16, const _Float16* __restrict__ Wt,
                     _Float16* __restrict__ X0, _Float16* __restrict__ X1, int nrows)
{
    // decode swizzled id: id = (xb & 7) + 8*(m + 4*(xb >> 3)); m = (col,z)
    const int b = blockIdx.x;
    const int inner = b >> 3;               // m + 4*(xb>>3)
    const int m = inner & 3;
    const int xb = ((inner >> 2) << 3) + (b & 7);
    if (xb >= NRB) return;
    const int yb = m & 1;                   // col block
    const int z  = m >> 1;                  // matrix

    const _Float16* W = Wt + z * 65536 + yb * (BN * 256);
    _Float16* X = z ? X1 : X0;
    const int row0 = xb * BM;
    const int col0 = yb * BN;

    // staging: As 64x64 (8 KB) + Bs 128x64 (16 KB) = 24 KB; epilogue reuses base.
    __shared__ __align__(1024) char smem[BM * BK * 2 + BN * BK * 2];   // 24576 B
    _Float16 (*As)[BK] = reinterpret_cast<_Float16 (*)[BK]>(smem);
    _Float16 (*Bs)[BK] = reinterpret_cast<_Float16 (*)[BK]>(smem + BM * BK * 2);
    _Float16* As_flat = reinterpret_cast<_Float16*>(smem);
    _Float16* Bs_flat = reinterpret_cast<_Float16*>(smem + BM * BK * 2);
    _Float16* ep = reinterpret_cast<_Float16*>(smem);

    const int tid  = threadIdx.x;
    const int wave = tid >> 6, lane = tid & 63;
    const int wy = wave >> 1, wx = wave & 1;
    const int quad = lane >> 4, l16 = lane & 15;

    float4_t acc[2][4];
    #pragma unroll
    for (int i = 0; i < 2; ++i)
        #pragma unroll
        for (int j = 0; j < 4; ++j) acc[i][j] = (float4_t)0.0f;

    // staging geometry: each 1 KB instruction covers 8 rows of a 64-col f16
    // tile; lane l -> row +(l>>3), 16B chunk (l&7) within the 128 B row.
    const int r_in  = lane >> 3;          // 0..7
    const int c_in  = (lane & 7) * 8;     // f16 offset within row: 0..56

    #pragma unroll
    for (int k0 = 0; k0 < 256; k0 += BK) {
        // A: 8 instrs (wave w issues 2), B: 16 instrs (wave w issues 4)
        #pragma unroll
        for (int j = 0; j < 2; ++j) {
            int ia  = wave * 2 + j;
            int row = ia * 8 + r_in;
            int gra = row0 + row;
            gra = (gra < nrows) ? gra : (nrows - 1);   // clamp; garbage rows never stored
            async_cp16(A16 + (size_t)gra * 256 + k0 + c_in, As_flat + ia * 512);
        }
        #pragma unroll
        for (int j = 0; j < 4; ++j) {
            int ib  = wave * 4 + j;
            int row = ib * 8 + r_in;
            async_cp16(W + (size_t)row * 256 + k0 + c_in, Bs_flat + ib * 512);
        }
        __syncthreads();

        #pragma unroll
        for (int s = 0; s < 2; ++s) {
            half8_t af[2], bf[4];
            #pragma unroll
            for (int i = 0; i < 2; ++i)
                af[i] = *reinterpret_cast<const half8_t*>(&As[wy * 32 + i * 16 + l16][s * 32 + quad * 8]);
            #pragma unroll
            for (int j = 0; j < 4; ++j)
                bf[j] = *reinterpret_cast<const half8_t*>(&Bs[wx * 64 + j * 16 + l16][s * 32 + quad * 8]);
            #pragma unroll
            for (int i = 0; i < 2; ++i)
                #pragma unroll
                for (int j = 0; j < 4; ++j)
                    acc[i][j] = __builtin_amdgcn_mfma_f32_16x16x32_f16(af[i], bf[j], acc[i][j], 0, 0, 0);
        }
        __syncthreads();   // final barrier also protects epilogue LDS reuse
    }

    // ---- epilogue: per-wave LDS transpose, 2 chunks of 16 rows x 64 cols ----
    _Float16* epw = ep + wave * 16 * EPAD2;          // 4 x 2304 B, disjoint
    #pragma unroll
    for (int it = 0; it < 2; ++it) {
        #pragma unroll
        for (int j = 0; j < 4; ++j)
            #pragma unroll
            for (int r = 0; r < 4; ++r)
                epw[(quad * 4 + r) * EPAD2 + j * 16 + l16] = (_Float16)acc[it][j][r];
        // wave-internal dependency only: no barrier needed
        #pragma unroll
        for (int p = 0; p < 2; ++p) {
            int row = p * 8 + (lane >> 3);           // 0..15
            int col = (lane & 7) * 8;                // 0..56
            int gr = row0 + wy * 32 + it * 16 + row;
            half8_t v = *reinterpret_cast<const half8_t*>(&epw[row * EPAD2 + col]);
            if (gr < nrows)
                *reinterpret_cast<half8_t*>(X + gr * 256 + col0 + wx * 64 + col) = v;
        }
    }
}

// ===== fused GATv2 edge phase + LayerNorm + ReLU, one WAVE per node =====
// 4 nodes per block; waves fully independent (no LDS, no barriers).
// Lane l covers channels 4l..4l+3 (within head l>>4); per-head score
// reduction = 4 DPP row_ror adds (VALU-only). 8 edges in flight per wave,
// with NEXT iteration's csr_src indices prefetched (software pipeline) so
// index-load latency is off the gather critical path. Masked 4-edge tail.
// Streaming softmax without max-subtraction (scores are O(+-5)).
__global__ __launch_bounds__(256)
void gat_fused_kernel(const _Float16* __restrict__ xl, const _Float16* __restrict__ xr,
                      const int* __restrict__ rowptr, const int* __restrict__ csr_src,
                      const float* __restrict__ att,
                      const float* __restrict__ bias, const float* __restrict__ g,
                      const float* __restrict__ be,
                      float* __restrict__ out32, _Float16* __restrict__ out16,
                      int write32)
{
    const int tid = threadIdx.x;
    const int w = tid >> 6, lane = tid & 63;
    const int n = blockIdx.x * 4 + w;
    const int start = rowptr[n], end = rowptr[n + 1];
    const int c0 = lane * 4;

    half2_t xr01, xr23, att01, att23;
    {
        half4_t xh = *reinterpret_cast<const half4_t*>(xr + n * D + c0);
        xr01.x = xh.x; xr01.y = xh.y; xr23.x = xh.z; xr23.y = xh.w;
        float4 av = *reinterpret_cast<const float4*>(att + c0);
        att01.x = (_Float16)av.x; att01.y = (_Float16)av.y;
        att23.x = (_Float16)av.z; att23.y = (_Float16)av.w;
    }
    const half2_t k02 = {(_Float16)NEG_SLOPE, (_Float16)NEG_SLOPE};

    float den = 0.0f;
    float4 num = make_float4(0.0f, 0.0f, 0.0f, 0.0f);

    int i = start;
    int nxt[8];
    if (i + 8 <= end) {
        #pragma unroll
        for (int j = 0; j < 8; ++j) nxt[j] = csr_src[i + j];
    }
    for (; i + 8 <= end; i += 8) {   // 8 edges in flight; indices prefetched
        int sidx[8];
        #pragma unroll
        for (int j = 0; j < 8; ++j) sidx[j] = nxt[j];
        // issue gathers for the current 8 edges immediately
        half4_t h[8];
        #pragma unroll
        for (int j = 0; j < 8; ++j)
            h[j] = *reinterpret_cast<const half4_t*>(xl + sidx[j] * D + c0);
        // prefetch next iteration's indices while gathers are in flight
        if (i + 16 <= end) {
            #pragma unroll
            for (int j = 0; j < 8; ++j) nxt[j] = csr_src[i + 8 + j];
        }
        float p[8];
        #pragma unroll
        for (int j = 0; j < 8; ++j) {
            half2_t a01 = {h[j].x, h[j].y}, a23 = {h[j].z, h[j].w};
            half2_t t0 = a01 + xr01, t1 = a23 + xr23;
            t0 = __builtin_elementwise_max(t0, t0 * k02);
            t1 = __builtin_elementwise_max(t1, t1 * k02);
            float v = __builtin_amdgcn_fdot2(t0, att01, 0.0f, false);
            p[j]    = __builtin_amdgcn_fdot2(t1, att23, v,   false);
        }
        #pragma unroll
        for (int j = 0; j < 8; ++j) p[j] = row_sum16(p[j]);
        #pragma unroll
        for (int j = 0; j < 8; ++j) p[j] = __expf(p[j]);
        #pragma unroll
        for (int j = 0; j < 8; ++j) {
            den += p[j];
            num.x = fmaf(p[j], (float)h[j].x, num.x);
            num.y = fmaf(p[j], (float)h[j].y, num.y);
            num.z = fmaf(p[j], (float)h[j].z, num.z);
            num.w = fmaf(p[j], (float)h[j].w, num.w);
        }
    }
    // masked tail: chunks of 4 (masks are wave-uniform; slack reads are safe)
    for (; i < end; i += 4) {
        int sidx[4];
        #pragma unroll
        for (int j = 0; j < 4; ++j) sidx[j] = csr_src[i + j];
        half4_t h[4];
        #pragma unroll
        for (int j = 0; j < 4; ++j)
            h[j] = *reinterpret_cast<const half4_t*>(xl + sidx[j] * D + c0);
        float p[4];
        #pragma unroll
        for (int j = 0; j < 4; ++j) {
            half2_t a01 = {h[j].x, h[j].y}, a23 = {h[j].z, h[j].w};
            half2_t t0 = a01 + xr01, t1 = a23 + xr23;
            t0 = __builtin_elementwise_max(t0, t0 * k02);
            t1 = __builtin_elementwise_max(t1, t1 * k02);
            float v = __builtin_amdgcn_fdot2(t0, att01, 0.0f, false);
            p[j]    = __builtin_amdgcn_fdot2(t1, att23, v,   false);
        }
        #pragma unroll
        for (int j = 0; j < 4; ++j) p[j] = row_sum16(p[j]);
        #pragma unroll
        for (int j = 0; j < 4; ++j) {
            float pj = (i + j < end) ? __expf(p[j]) : 0.0f;
            den += pj;
            num.x = fmaf(pj, (float)h[j].x, num.x);
            num.y = fmaf(pj, (float)h[j].y, num.y);
            num.z = fmaf(pj, (float)h[j].z, num.z);
            num.w = fmaf(pj, (float)h[j].w, num.w);
        }
    }

    // normalize + bias (den is already per-head correct for this lane)
    float inv_den = 1.0f / den;
    float4 bi = *reinterpret_cast<const float4*>(bias + c0);
    float a0 = fmaf(num.x, inv_den, bi.x);
    float a1 = fmaf(num.y, inv_den, bi.y);
    float a2 = fmaf(num.z, inv_den, bi.z);
    float a3 = fmaf(num.w, inv_den, bi.w);

    // LayerNorm over 256 channels: in-lane partial + 6-step butterfly
    float wsum = a0 + a1 + a2 + a3;
    float wsq  = a0 * a0 + a1 * a1 + a2 * a2 + a3 * a3;
    #pragma unroll
    for (int o = 1; o < 64; o <<= 1) {
        wsum += __shfl_xor(wsum, o, 64);
        wsq  += __shfl_xor(wsq,  o, 64);
    }
    float mu = wsum * (1.0f / 256.0f);
    float var = wsq * (1.0f / 256.0f) - mu * mu;
    float rstd = rsqrtf(var + LN_EPS);

    float4 gg = *reinterpret_cast<const float4*>(g + c0);
    float4 bb = *reinterpret_cast<const float4*>(be + c0);
    float o0 = fmaxf((a0 - mu) * rstd * gg.x + bb.x, 0.0f);
    float o1 = fmaxf((a1 - mu) * rstd * gg.y + bb.y, 0.0f);
    float o2 = fmaxf((a2 - mu) * rstd * gg.z + bb.z, 0.0f);
    float o3 = fmaxf((a3 - mu) * rstd * gg.w + bb.w, 0.0f);

    if (write32) {
        float4 o4 = make_float4(o0, o1, o2, o3);
        *reinterpret_cast<float4*>(out32 + n * D + c0) = o4;
    } else {
        half4_t o4;
        o4.x = (_Float16)o0; o4.y = (_Float16)o1; o4.z = (_Float16)o2; o4.w = (_Float16)o3;
        *reinterpret_cast<half4_t*>(out16 + n * D + c0) = o4;
    }
}

// ================= launch =================
extern "C" void kernel_launch(void* const* d_in, const int* in_sizes, int n_in,
                              void* d_out, int out_size, void* d_ws, size_t ws_size,
                              hipStream_t stream)
{
    const float* x  = (const float*)d_in[0];
    const int*   ei = (const int*)d_in[1];

    char* ws = (char*)d_ws;
    size_t off = 0;
    _Float16* h16   = (_Float16*)(ws + off); off += (size_t)N_NODES * D * 2;      // 10.24 MB
    _Float16* xl    = (_Float16*)(ws + off); off += (size_t)N_NODES * D * 2;      // 10.24 MB
    _Float16* xr    = (_Float16*)(ws + off); off += (size_t)N_NODES * D * 2;      // 10.24 MB
    _Float16* WtA   = (_Float16*)(ws + off); off += (size_t)8 * 65536 * 2;        // 1 MB
    int* rowptr     = (int*)(ws + off);      off += (size_t)(N_NODES + 32) * 4;
    int* cursor     = (int*)(ws + off);      off += (size_t)N_NODES * 4;
    int* csr_src    = (int*)(ws + off);      off += (size_t)(EP + 32) * 4;

    WPtrs wp;
    for (int l = 0; l < 4; ++l) {
        wp.p[2 * l + 0] = (const float*)d_in[2 + 6 * l + 0];
        wp.p[2 * l + 1] = (const float*)d_in[2 + 6 * l + 1];
    }

    // one-time per call
    hipMemsetAsync(cursor, 0, (size_t)N_NODES * 4, stream);          // deg = 0
    convert_hist_kernel<<<(N_NODES * D / 4 + 255) / 256, 256, 0, stream>>>(x, h16, ei, cursor);
    csr_scan_kernel<<<1, 1024, 0, stream>>>(cursor, rowptr, cursor, csr_src);
    scatter_convw_kernel<<<SCATTER_BLOCKS + 128, 256, 0, stream>>>(ei, cursor, csr_src, wp, WtA);

    // gemm grid: swizzled flat ids cover xb in [0,313), m in [0,4): 8*(4*40) = 1280
    const int gemm_blocks = 8 * 4 * ((NRB + 7) / 8);   // 1280

    for (int l = 0; l < 4; ++l) {
        const float* att  = (const float*)d_in[2 + 6 * l + 2];
        const float* bias = (const float*)d_in[2 + 6 * l + 3];
        const float* g    = (const float*)d_in[2 + 6 * l + 4];
        const float* be   = (const float*)d_in[2 + 6 * l + 5];

        gemm_f16_kernel<<<gemm_blocks, 256, 0, stream>>>(h16, WtA + (size_t)l * 131072,
                                                         xl, xr, N_NODES);
        gat_fused_kernel<<<N_NODES / 4, 256, 0, stream>>>(xl, xr, rowptr, csr_src, att,
                                                          bias, g, be,
                                                          (float*)d_out, h16, (l == 3) ? 1 : 0);
    }
}

// Round 16
// 322.859 us; speedup vs baseline: 1.0257x; 1.0257x over previous
//
#include <hip/hip_runtime.h>
#include <math.h>

#define N_NODES 20000
#define E_EDGES 320000
#define EP (E_EDGES + N_NODES)   // 340000 edges incl. self-loops
#define D 256
#define NHEAD 4
#define CH 64
#define NEG_SLOPE 0.2f
#define LN_EPS 1e-5f

typedef _Float16 half8_t __attribute__((ext_vector_type(8)));
typedef _Float16 half4_t __attribute__((ext_vector_type(4)));
typedef _Float16 half2_t __attribute__((ext_vector_type(2)));
typedef float   float4_t __attribute__((ext_vector_type(4)));

#define SCATTER_BLOCKS ((EP + 255) / 256)   // 1329

__device__ __forceinline__ void async_cp16(const void* g, void* l)
{
    __builtin_amdgcn_global_load_lds(
        (const __attribute__((address_space(1))) void*)g,
        (__attribute__((address_space(3))) void*)l, 16, 0, 0);
}

// ---- DPP row_ror reduction over 16-lane rows (pure VALU, no LDS pipe) ----
template<int CTRL>
__device__ __forceinline__ float dpp_add(float v) {
    int t = __builtin_amdgcn_update_dpp(0, __float_as_int(v), CTRL, 0xF, 0xF, true);
    return v + __int_as_float(t);
}
__device__ __forceinline__ float row_sum16(float v) {
    v = dpp_add<0x121>(v);   // ror 1
    v = dpp_add<0x122>(v);   // ror 2
    v = dpp_add<0x124>(v);   // ror 4
    v = dpp_add<0x128>(v);   // ror 8
    return v;
}

// ===== one-time: convert x (fp32) -> f16 AND histogram degrees =====
// (deg must be pre-zeroed via hipMemsetAsync before this kernel)
__global__ __launch_bounds__(256)
void convert_hist_kernel(const float* __restrict__ x, _Float16* __restrict__ h16,
                         const int* __restrict__ ei, int* __restrict__ deg)
{
    int i = blockIdx.x * 256 + threadIdx.x;
    if (i < EP) {
        int dst = (i < E_EDGES) ? ei[E_EDGES + i] : (i - E_EDGES);
        atomicAdd(&deg[dst], 1);
    }
    if (i >= N_NODES * D / 4) return;
    float4 v = reinterpret_cast<const float4*>(x)[i];
    half4_t o;
    o.x = (_Float16)v.x; o.y = (_Float16)v.y; o.z = (_Float16)v.z; o.w = (_Float16)v.w;
    reinterpret_cast<half4_t*>(h16)[i] = o;
}

// single-pass block scan, LDS-staged for coalesced global access.
// 4 chunks of 5120 nodes; thread t owns 5 consecutive nodes per chunk.
__global__ __launch_bounds__(1024)
void csr_scan_kernel(const int* __restrict__ deg, int* __restrict__ rowptr,
                     int* __restrict__ cursor, int* __restrict__ csr_src)
{
    __shared__ int buf[5120];
    __shared__ int wsum[16];
    __shared__ int carry_s;
    int t = threadIdx.x, lane = t & 63, w = t >> 6;
    if (t == 0) carry_s = 0;
    if (t < 8) csr_src[EP + t] = 0;      // slack for masked tail over-reads

    for (int c = 0; c < 4; ++c) {
        int base = c * 5120;
        // coalesced load (stride-1 across lanes)
        #pragma unroll
        for (int k = 0; k < 5; ++k) {
            int idx = base + k * 1024 + t;
            buf[k * 1024 + t] = (idx < N_NODES) ? deg[idx] : 0;
        }
        __syncthreads();
        int loc[5]; int s = 0;
        #pragma unroll
        for (int k = 0; k < 5; ++k) { loc[k] = buf[t * 5 + k]; s += loc[k]; }
        int x = s;
        #pragma unroll
        for (int o = 1; o < 64; o <<= 1) {
            int y = __shfl_up(x, o, 64);
            if (lane >= o) x += y;
        }
        if (lane == 63) wsum[w] = x;
        __syncthreads();                  // also: all lanes done reading buf
        if (t == 0) {
            int sa = carry_s;
            #pragma unroll
            for (int k = 0; k < 16; ++k) { int tmp = wsum[k]; wsum[k] = sa; sa += tmp; }
            carry_s = sa;
        }
        __syncthreads();
        int excl = wsum[w] + x - s;
        #pragma unroll
        for (int k = 0; k < 5; ++k) { buf[t * 5 + k] = excl; excl += loc[k]; }
        __syncthreads();
        // coalesced store of rowptr and cursor
        #pragma unroll
        for (int k = 0; k < 5; ++k) {
            int idx = base + k * 1024 + t;
            if (idx < N_NODES) {
                int v = buf[k * 1024 + t];
                rowptr[idx] = v;
                cursor[idx] = v;
            }
        }
        __syncthreads();                  // buf reused next chunk
    }
    if (t == 0) rowptr[N_NODES] = carry_s;
}

// ===== fused: CSR scatter (blocks < SCATTER_BLOCKS) + weight convert/transpose =====
struct WPtrs { const float* p[8]; };
__global__ __launch_bounds__(256)
void scatter_convw_kernel(const int* __restrict__ ei, int* __restrict__ cursor,
                          int* __restrict__ csr_src, WPtrs wp,
                          _Float16* __restrict__ Wt_all)
{
    if (blockIdx.x < SCATTER_BLOCKS) {
        int e = blockIdx.x * 256 + threadIdx.x;
        if (e >= EP) return;
        int src, dst;
        if (e < E_EDGES) { src = ei[e]; dst = ei[E_EDGES + e]; }
        else             { src = dst = e - E_EDGES; }
        int pos = atomicAdd(&cursor[dst], 1);
        csr_src[pos] = src;
        return;
    }
    // weight convert: 128 blocks mapped to (bx, by, z) = (4, 4, 8)
    __shared__ float tile[64][65];
    int bz = blockIdx.x - SCATTER_BLOCKS;
    int bxi = bz & 3, byi = (bz >> 2) & 3, z = bz >> 4;
    const float* W = wp.p[z];
    _Float16* out = Wt_all + (size_t)z * 65536;
    int bx = bxi * 64, by = byi * 64;
    int t = threadIdx.x;
    #pragma unroll
    for (int i = 0; i < 16; ++i) {
        int idx = t + i * 256;
        int kk = idx >> 6, nn = idx & 63;
        tile[kk][nn] = W[(by + kk) * 256 + bx + nn];
    }
    __syncthreads();
    #pragma unroll
    for (int i = 0; i < 16; ++i) {
        int idx = t + i * 256;
        int nn = idx >> 6, kk = idx & 63;
        out[(bx + nn) * 256 + by + kk] = (_Float16)tile[kk][nn];
    }
}

// ================= GEMM: X = A16 @ W (f16 MFMA, fp32 accum, f16 out) =================
// A16: [M][256] f16 row-major; Wt: [256][256] f16 laid out [n][k].
// 1-D grid of 640 (12 idle); flat id is XCD-pair-swizzled so the two blocks
// (x,y,z=0) and (x,y,z=1) -- which read the SAME A tile -- share id mod 8
// and land on the same XCD (A tile fetched into that L2 once).
// BM=128, BN=128, BK=64. 4 waves as 2x2: wave (wy,wx) owns 64x64.
#define BM 128
#define BN 128
#define BK 64
#define EPAD2 72   // epilogue LDS row stride in f16 (144 B)
__global__ __launch_bounds__(256)
void gemm_f16_kernel(const _Float16* __restrict__ A16, const _Float16* __restrict__ Wt,
                     _Float16* __restrict__ X0, _Float16* __restrict__ X1, int nrows)
{
    // decode swizzled flat id: pair = (b>>4)*8 + (b&7), z = (b>>3)&1
    const int b = blockIdx.x;
    const int pair = ((b >> 4) << 3) + (b & 7);
    const int z = (b >> 3) & 1;
    if (pair >= 314) return;
    const int yb = (pair >= 157) ? 1 : 0;
    const int xb = pair - yb * 157;

    const _Float16* W = Wt + z * 65536 + yb * (BN * 256);
    _Float16* X = z ? X1 : X0;
    const int row0 = xb * BM;
    const int col0 = yb * BN;

    // staging: As 128x64 + Bs 128x64 f16 = 32 KB; epilogue reuses base region.
    __shared__ __align__(1024) char smem[BM * BK * 2 + BN * BK * 2];   // 32768 B
    _Float16 (*As)[BK] = reinterpret_cast<_Float16 (*)[BK]>(smem);
    _Float16 (*Bs)[BK] = reinterpret_cast<_Float16 (*)[BK]>(smem + BM * BK * 2);
    _Float16* As_flat = reinterpret_cast<_Float16*>(smem);
    _Float16* Bs_flat = reinterpret_cast<_Float16*>(smem + BM * BK * 2);
    _Float16* ep = reinterpret_cast<_Float16*>(smem);

    const int tid  = threadIdx.x;
    const int wave = tid >> 6, lane = tid & 63;
    const int wy = wave >> 1, wx = wave & 1;
    const int quad = lane >> 4, l16 = lane & 15;

    float4_t acc[4][4];
    #pragma unroll
    for (int i = 0; i < 4; ++i)
        #pragma unroll
        for (int j = 0; j < 4; ++j) acc[i][j] = (float4_t)0.0f;

    // staging geometry: each 1 KB instruction covers 8 rows of a 64-col f16
    // tile; lane l -> row +(l>>3), 16B chunk (l&7) within the 128 B row.
    const int r_in  = lane >> 3;          // 0..7
    const int c_in  = (lane & 7) * 8;     // f16 offset within row: 0..56

    #pragma unroll
    for (int k0 = 0; k0 < 256; k0 += BK) {
        // A: 16 instrs; wave w issues ia = 4w..4w+3.  B: same.
        #pragma unroll
        for (int j = 0; j < 4; ++j) {
            int ia  = wave * 4 + j;
            int row = ia * 8 + r_in;
            int gra = row0 + row;
            gra = (gra < nrows) ? gra : (nrows - 1);   // clamp; garbage rows never stored
            async_cp16(A16 + (size_t)gra * 256 + k0 + c_in, As_flat + ia * 512);
            async_cp16(W   + (size_t)row * 256 + k0 + c_in, Bs_flat + ia * 512);
        }
        __syncthreads();

        #pragma unroll
        for (int s = 0; s < 2; ++s) {
            half8_t af[4], bf[4];
            #pragma unroll
            for (int i = 0; i < 4; ++i)
                af[i] = *reinterpret_cast<const half8_t*>(&As[wy * 64 + i * 16 + l16][s * 32 + quad * 8]);
            #pragma unroll
            for (int j = 0; j < 4; ++j)
                bf[j] = *reinterpret_cast<const half8_t*>(&Bs[wx * 64 + j * 16 + l16][s * 32 + quad * 8]);
            #pragma unroll
            for (int i = 0; i < 4; ++i)
                #pragma unroll
                for (int j = 0; j < 4; ++j)
                    acc[i][j] = __builtin_amdgcn_mfma_f32_16x16x32_f16(af[i], bf[j], acc[i][j], 0, 0, 0);
        }
        __syncthreads();   // final barrier also protects epilogue LDS reuse
    }

    // ---- epilogue: per-wave LDS transpose, 4 chunks of 16 rows x 64 cols ----
    _Float16* epw = ep + wave * 16 * EPAD2;          // 4 x 2304 B, disjoint
    #pragma unroll
    for (int it = 0; it < 4; ++it) {
        #pragma unroll
        for (int j = 0; j < 4; ++j)
            #pragma unroll
            for (int r = 0; r < 4; ++r)
                epw[(quad * 4 + r) * EPAD2 + j * 16 + l16] = (_Float16)acc[it][j][r];
        // wave-internal dependency only: no barrier needed
        #pragma unroll
        for (int p = 0; p < 2; ++p) {
            int row = p * 8 + (lane >> 3);           // 0..15
            int col = (lane & 7) * 8;                // 0..56
            int gr = row0 + wy * 64 + it * 16 + row;
            half8_t v = *reinterpret_cast<const half8_t*>(&epw[row * EPAD2 + col]);
            if (gr < nrows)
                *reinterpret_cast<half8_t*>(X + gr * 256 + col0 + wx * 64 + col) = v;
        }
    }
}

// ===== fused GATv2 edge phase + LayerNorm + ReLU, one WAVE per node =====
// 4 nodes per block; waves fully independent (no LDS, no barriers).
// Lane l covers channels 4l..4l+3 (within head l>>4); per-head score
// reduction = 4 DPP row_ror adds (VALU-only). 8 edges in flight per wave,
// with NEXT iteration's csr_src indices prefetched (software pipeline) so
// index-load latency is off the gather critical path. Masked 4-edge tail.
// Streaming softmax without max-subtraction (scores are O(+-5)).
__global__ __launch_bounds__(256)
void gat_fused_kernel(const _Float16* __restrict__ xl, const _Float16* __restrict__ xr,
                      const int* __restrict__ rowptr, const int* __restrict__ csr_src,
                      const float* __restrict__ att,
                      const float* __restrict__ bias, const float* __restrict__ g,
                      const float* __restrict__ be,
                      float* __restrict__ out32, _Float16* __restrict__ out16,
                      int write32)
{
    const int tid = threadIdx.x;
    const int w = tid >> 6, lane = tid & 63;
    const int n = blockIdx.x * 4 + w;
    const int start = rowptr[n], end = rowptr[n + 1];
    const int c0 = lane * 4;

    half2_t xr01, xr23, att01, att23;
    {
        half4_t xh = *reinterpret_cast<const half4_t*>(xr + n * D + c0);
        xr01.x = xh.x; xr01.y = xh.y; xr23.x = xh.z; xr23.y = xh.w;
        float4 av = *reinterpret_cast<const float4*>(att + c0);
        att01.x = (_Float16)av.x; att01.y = (_Float16)av.y;
        att23.x = (_Float16)av.z; att23.y = (_Float16)av.w;
    }
    const half2_t k02 = {(_Float16)NEG_SLOPE, (_Float16)NEG_SLOPE};

    float den = 0.0f;
    float4 num = make_float4(0.0f, 0.0f, 0.0f, 0.0f);

    int i = start;
    int nxt[8];
    if (i + 8 <= end) {
        #pragma unroll
        for (int j = 0; j < 8; ++j) nxt[j] = csr_src[i + j];
    }
    for (; i + 8 <= end; i += 8) {   // 8 edges in flight; indices prefetched
        int sidx[8];
        #pragma unroll
        for (int j = 0; j < 8; ++j) sidx[j] = nxt[j];
        // issue gathers for the current 8 edges immediately
        half4_t h[8];
        #pragma unroll
        for (int j = 0; j < 8; ++j)
            h[j] = *reinterpret_cast<const half4_t*>(xl + sidx[j] * D + c0);
        // prefetch next iteration's indices while gathers are in flight
        if (i + 16 <= end) {
            #pragma unroll
            for (int j = 0; j < 8; ++j) nxt[j] = csr_src[i + 8 + j];
        }
        float p[8];
        #pragma unroll
        for (int j = 0; j < 8; ++j) {
            half2_t a01 = {h[j].x, h[j].y}, a23 = {h[j].z, h[j].w};
            half2_t t0 = a01 + xr01, t1 = a23 + xr23;
            t0 = __builtin_elementwise_max(t0, t0 * k02);
            t1 = __builtin_elementwise_max(t1, t1 * k02);
            float v = __builtin_amdgcn_fdot2(t0, att01, 0.0f, false);
            p[j]    = __builtin_amdgcn_fdot2(t1, att23, v,   false);
        }
        #pragma unroll
        for (int j = 0; j < 8; ++j) p[j] = row_sum16(p[j]);
        #pragma unroll
        for (int j = 0; j < 8; ++j) p[j] = __expf(p[j]);
        #pragma unroll
        for (int j = 0; j < 8; ++j) {
            den += p[j];
            num.x = fmaf(p[j], (float)h[j].x, num.x);
            num.y = fmaf(p[j], (float)h[j].y, num.y);
            num.z = fmaf(p[j], (float)h[j].z, num.z);
            num.w = fmaf(p[j], (float)h[j].w, num.w);
        }
    }
    // masked tail: chunks of 4 (masks are wave-uniform; slack reads are safe)
    for (; i < end; i += 4) {
        int sidx[4];
        #pragma unroll
        for (int j = 0; j < 4; ++j) sidx[j] = csr_src[i + j];
        half4_t h[4];
        #pragma unroll
        for (int j = 0; j < 4; ++j)
            h[j] = *reinterpret_cast<const half4_t*>(xl + sidx[j] * D + c0);
        float p[4];
        #pragma unroll
        for (int j = 0; j < 4; ++j) {
            half2_t a01 = {h[j].x, h[j].y}, a23 = {h[j].z, h[j].w};
            half2_t t0 = a01 + xr01, t1 = a23 + xr23;
            t0 = __builtin_elementwise_max(t0, t0 * k02);
            t1 = __builtin_elementwise_max(t1, t1 * k02);
            float v = __builtin_amdgcn_fdot2(t0, att01, 0.0f, false);
            p[j]    = __builtin_amdgcn_fdot2(t1, att23, v,   false);
        }
        #pragma unroll
        for (int j = 0; j < 4; ++j) p[j] = row_sum16(p[j]);
        #pragma unroll
        for (int j = 0; j < 4; ++j) {
            float pj = (i + j < end) ? __expf(p[j]) : 0.0f;
            den += pj;
            num.x = fmaf(pj, (float)h[j].x, num.x);
            num.y = fmaf(pj, (float)h[j].y, num.y);
            num.z = fmaf(pj, (float)h[j].z, num.z);
            num.w = fmaf(pj, (float)h[j].w, num.w);
        }
    }

    // normalize + bias (den is already per-head correct for this lane)
    float inv_den = 1.0f / den;
    float4 bi = *reinterpret_cast<const float4*>(bias + c0);
    float a0 = fmaf(num.x, inv_den, bi.x);
    float a1 = fmaf(num.y, inv_den, bi.y);
    float a2 = fmaf(num.z, inv_den, bi.z);
    float a3 = fmaf(num.w, inv_den, bi.w);

    // LayerNorm over 256 channels: in-lane partial + 6-step butterfly
    float wsum = a0 + a1 + a2 + a3;
    float wsq  = a0 * a0 + a1 * a1 + a2 * a2 + a3 * a3;
    #pragma unroll
    for (int o = 1; o < 64; o <<= 1) {
        wsum += __shfl_xor(wsum, o, 64);
        wsq  += __shfl_xor(wsq,  o, 64);
    }
    float mu = wsum * (1.0f / 256.0f);
    float var = wsq * (1.0f / 256.0f) - mu * mu;
    float rstd = rsqrtf(var + LN_EPS);

    float4 gg = *reinterpret_cast<const float4*>(g + c0);
    float4 bb = *reinterpret_cast<const float4*>(be + c0);
    float o0 = fmaxf((a0 - mu) * rstd * gg.x + bb.x, 0.0f);
    float o1 = fmaxf((a1 - mu) * rstd * gg.y + bb.y, 0.0f);
    float o2 = fmaxf((a2 - mu) * rstd * gg.z + bb.z, 0.0f);
    float o3 = fmaxf((a3 - mu) * rstd * gg.w + bb.w, 0.0f);

    if (write32) {
        float4 o4 = make_float4(o0, o1, o2, o3);
        *reinterpret_cast<float4*>(out32 + n * D + c0) = o4;
    } else {
        half4_t o4;
        o4.x = (_Float16)o0; o4.y = (_Float16)o1; o4.z = (_Float16)o2; o4.w = (_Float16)o3;
        *reinterpret_cast<half4_t*>(out16 + n * D + c0) = o4;
    }
}

// ================= launch =================
extern "C" void kernel_launch(void* const* d_in, const int* in_sizes, int n_in,
                              void* d_out, int out_size, void* d_ws, size_t ws_size,
                              hipStream_t stream)
{
    const float* x  = (const float*)d_in[0];
    const int*   ei = (const int*)d_in[1];

    char* ws = (char*)d_ws;
    size_t off = 0;
    _Float16* h16   = (_Float16*)(ws + off); off += (size_t)N_NODES * D * 2;      // 10.24 MB
    _Float16* xl    = (_Float16*)(ws + off); off += (size_t)N_NODES * D * 2;      // 10.24 MB
    _Float16* xr    = (_Float16*)(ws + off); off += (size_t)N_NODES * D * 2;      // 10.24 MB
    _Float16* WtA   = (_Float16*)(ws + off); off += (size_t)8 * 65536 * 2;        // 1 MB
    int* rowptr     = (int*)(ws + off);      off += (size_t)(N_NODES + 32) * 4;
    int* cursor     = (int*)(ws + off);      off += (size_t)N_NODES * 4;
    int* csr_src    = (int*)(ws + off);      off += (size_t)(EP + 32) * 4;

    WPtrs wp;
    for (int l = 0; l < 4; ++l) {
        wp.p[2 * l + 0] = (const float*)d_in[2 + 6 * l + 0];
        wp.p[2 * l + 1] = (const float*)d_in[2 + 6 * l + 1];
    }

    // one-time per call
    hipMemsetAsync(cursor, 0, (size_t)N_NODES * 4, stream);          // deg = 0
    convert_hist_kernel<<<(N_NODES * D / 4 + 255) / 256, 256, 0, stream>>>(x, h16, ei, cursor);
    csr_scan_kernel<<<1, 1024, 0, stream>>>(cursor, rowptr, cursor, csr_src);
    scatter_convw_kernel<<<SCATTER_BLOCKS + 128, 256, 0, stream>>>(ei, cursor, csr_src, wp, WtA);

    for (int l = 0; l < 4; ++l) {
        const float* att  = (const float*)d_in[2 + 6 * l + 2];
        const float* bias = (const float*)d_in[2 + 6 * l + 3];
        const float* g    = (const float*)d_in[2 + 6 * l + 4];
        const float* be   = (const float*)d_in[2 + 6 * l + 5];

        gemm_f16_kernel<<<640, 256, 0, stream>>>(h16, WtA + (size_t)l * 131072,
                                                 xl, xr, N_NODES);
        gat_fused_kernel<<<N_NODES / 4, 256, 0, stream>>>(xl, xr, rowptr, csr_src, att,
                                                          bias, g, be,
                                                          (float*)d_out, h16, (l == 3) ? 1 : 0);
    }
}